// Round 6
// baseline (74.435 us; speedup 1.0000x reference)
//
#include <hip/hip_runtime.h>
#include <hip/hip_bf16.h>

// Quantized int8 3x3 conv via implicit-im2col MFMA (mfma_i32_32x32x32_i8).
// out = 1e-4*dot + asumf[px] + bconst[co]
//
// Round-6 structure:
//   - block owns 2 output rows (108 px) x 128 couts; grid (27 rowpairs, 32 n, 2 ctile)
//   - input slab (4 rows x 56 x 128 = 28KB) staged ONCE per block, XOR-swizzled
//     (pre-swizzled global source + linear LDS dest; readers apply same XOR)
//   - weights L2->registers, step-major wq3[tap][kk][h][co][16B]; per-tap
//     register double-buffer prefetch (manual software pipeline, static idx)
//   - 32x32x32 i8 MFMA: wave tile 64co x 64px = m2 x p2 x kk4, 16 MFMA/tap
//   - no barriers in the 9-tap main loop; s_setprio(1) around MFMA cluster

#define N_B   32
#define C_IN  128
#define H_IN  56
#define W_IN  56
#define C_OUT 256
#define H_OUT 54
#define W_OUT 54
#define K_TOT 1152
#define NPX   (N_B * H_OUT * W_OUT)   // 93312
#define PXROW (H_OUT * W_OUT)         // 2916

using i32x4  = __attribute__((ext_vector_type(4))) int;
using i32x16 = __attribute__((ext_vector_type(16))) int;

static __device__ __forceinline__ int dot4(int a, int b, int c) {
#if __has_builtin(__builtin_amdgcn_sdot4)
  return __builtin_amdgcn_sdot4(a, b, c, false);
#else
  signed char a0 = (signed char)a, a1 = (signed char)(a >> 8),
              a2 = (signed char)(a >> 16), a3 = (signed char)(a >> 24);
  signed char b0 = (signed char)b, b1 = (signed char)(b >> 8),
              b2 = (signed char)(b >> 16), b3 = (signed char)(b >> 24);
  return c + a0 * b0 + a1 * b1 + a2 * b2 + a3 * b3;
#endif
}

__device__ __forceinline__ void gload16(const void* g, void* l) {
  __builtin_amdgcn_global_load_lds(
      (const __attribute__((address_space(1))) void*)g,
      (__attribute__((address_space(3))) void*)l, 16, 0, 0);
}

// ---------------- weight repack: OIHW(int32) -> wq3[t][kk][h][co][16] i8, bconst
// ci = kk*32 + h*16 + b  ->  offset = t*32768 + kk*8192 + h*4096 + co*16 + b
__global__ void repack_w(const int* __restrict__ w, const float* __restrict__ bias,
                         signed char* __restrict__ wq3, float* __restrict__ bconst) {
  int co = blockIdx.x;    // 256
  int ci = threadIdx.x;   // 128
  const int* wrow = w + (size_t)co * K_TOT + (size_t)ci * 9;
  int s = 0;
  int kk = ci >> 5, h = (ci >> 4) & 1, b = ci & 15;
  size_t base = (size_t)kk * 8192 + h * 4096 + co * 16 + b;
#pragma unroll
  for (int t = 0; t < 9; ++t) {
    int v = wrow[t];
    s += v;
    wq3[(size_t)t * 32768 + base] = (signed char)v;
  }
  __shared__ int red[128];
  red[ci] = s;
  __syncthreads();
  for (int off = 64; off > 0; off >>= 1) {
    if (ci < off) red[ci] += red[ci + off];
    __syncthreads();
  }
  if (ci == 0) {
    int wsum = red[0];
    float r = rintf(bias[co] / 0.0001f);                 // round half-even
    r = fminf(fmaxf(r, -2147483648.0f), 2147483647.0f);  // clamp to i32 range
    bconst[co] = 1e-4f * (float)(-7 * wsum + 24192) + r * 0.0001f;
  }
}

// ---------------- input repack: NCHW(int32) -> NHWC int8, fused per-px channel sums
__global__ void repack_in(const int* __restrict__ in, signed char* __restrict__ ip,
                          int* __restrict__ rs) {
  __shared__ int t32[C_IN * W_IN];   // 28KB
  __shared__ int rsum[W_IN];
  int h = blockIdx.x, n = blockIdx.y;
  int tid = threadIdx.x;
  if (tid < W_IN) rsum[tid] = 0;

  int ci = tid >> 1, hf = tid & 1;
  const int* s = in + ((size_t)n * C_IN + ci) * (H_IN * W_IN) + h * W_IN + hf * 28;
  int* d = &t32[ci * W_IN + hf * 28];
#pragma unroll
  for (int k = 0; k < 7; ++k)
    *(int4*)(d + k * 4) = *(const int4*)(s + k * 4);
  __syncthreads();

  signed char* dst = ip + (((size_t)n * H_IN + h) * W_IN) * C_IN;
  for (int j = tid; j < 448; j += 256) {
    int w = j >> 3, c16 = j & 7;
    int b[4], srow = 0;
#pragma unroll
    for (int q = 0; q < 4; ++q) {
      int x0 = t32[(c16 * 16 + q * 4 + 0) * W_IN + w];
      int x1 = t32[(c16 * 16 + q * 4 + 1) * W_IN + w];
      int x2 = t32[(c16 * 16 + q * 4 + 2) * W_IN + w];
      int x3 = t32[(c16 * 16 + q * 4 + 3) * W_IN + w];
      b[q] = (x0 & 255) | ((x1 & 255) << 8) | ((x2 & 255) << 16) | ((x3 & 255) << 24);
      srow = dot4(b[q], 0x01010101, srow);
    }
    *(int4*)(dst + (size_t)j * 16) = *(int4*)b;
    atomicAdd(&rsum[w], srow);
  }
  __syncthreads();
  if (tid < W_IN) rs[((size_t)n * H_IN + h) * W_IN + tid] = rsum[tid];
}

// ---------------- per-output-pixel: asumf = -3e-4 * receptive-field sum
__global__ void asum_k(const int* __restrict__ rs, float* __restrict__ asumf) {
  int px = blockIdx.x * 256 + threadIdx.x;
  if (px >= NPX) return;
  int n = px / PXROW, rem = px - n * PXROW;
  int y = rem / W_OUT, x = rem - y * W_OUT;
  const int* rp = rs + ((size_t)n * H_IN + y) * W_IN + x;
  int s = 0;
#pragma unroll
  for (int kh = 0; kh < 3; ++kh)
    s += rp[kh * W_IN + 0] + rp[kh * W_IN + 1] + rp[kh * W_IN + 2];
  asumf[px] = -3e-4f * (float)s;
}

// ---------------- main MFMA conv
__launch_bounds__(256, 3)
__global__ void conv_mfma(const signed char* __restrict__ ip,
                          const signed char* __restrict__ wq3,
                          const float* __restrict__ asumf,
                          const float* __restrict__ bconst,
                          float* __restrict__ out) {
  __shared__ signed char lds[28672];  // B slab only
  const int tid = threadIdx.x, w = tid >> 6, l = tid & 63;
  const int wr = w >> 1, wc = w & 1;
  const int rp = blockIdx.x;           // row pair 0..26
  const int n  = blockIdx.y;           // 0..31
  const int ct = blockIdx.z;           // co tile 0..1
  const int y0 = rp * 2;

  // ---- stage B slab (4 input rows, 28KB), pre-swizzled source, linear dest
  const signed char* slab = ip + ((size_t)(n * H_IN + y0) * W_IN) * C_IN;
  const int sw = ((tid >> 3) & 7) << 4;        // (L>>7)&7 is i-invariant
#pragma unroll
  for (int i = 0; i < 7; ++i) {
    int L = i * 4096 + tid * 16;
    gload16(slab + (L ^ sw), &lds[L]);
  }

  // ---- per-lane B pixel bases: p-frag pf covers px j = wc*64 + pf*32 + (l&31)
  int psb[2], jv[2];
#pragma unroll
  for (int pf = 0; pf < 2; ++pf) {
    int j = wc * 64 + pf * 32 + (l & 31);
    jv[pf] = j;
    if (j > 107) j = 107;               // dead lanes clamp (stores guarded)
    int dy = (j >= 54) ? 1 : 0;
    psb[pf] = dy * 56 + (j - dy * 54);
  }
  const int h16 = (l >> 5) * 16;        // k-chunk byte offset within 32-k block

  // ---- A fragment source: co = ct*128 + wr*64 + m*32 + (l&31), k-chunk h = l>>5
  const signed char* awq = wq3 + (size_t)(l >> 5) * 4096 +
                           (size_t)(ct * 128 + wr * 64 + (l & 31)) * 16;

  i32x16 acc[2][2];
#pragma unroll
  for (int m = 0; m < 2; ++m)
#pragma unroll
    for (int pf = 0; pf < 2; ++pf)
#pragma unroll
      for (int r = 0; r < 16; ++r) acc[m][pf][r] = 0;

  // ---- prefetch tap 0 A fragments into register buffer 0
  i32x4 af[2][4][2];
#pragma unroll
  for (int kk = 0; kk < 4; ++kk)
#pragma unroll
    for (int m = 0; m < 2; ++m)
      af[0][kk][m] = *(const i32x4*)(awq + kk * 8192 + m * 512);

  __syncthreads();   // slab staged — the ONLY barrier

#pragma unroll
  for (int t = 0; t < 9; ++t) {
    if (t < 8) {     // prefetch tap t+1 into the other register buffer
#pragma unroll
      for (int kk = 0; kk < 4; ++kk)
#pragma unroll
        for (int m = 0; m < 2; ++m)
          af[(t + 1) & 1][kk][m] =
              *(const i32x4*)(awq + (size_t)(t + 1) * 32768 + kk * 8192 + m * 512);
    }
    const int dlt = (t / 3) * 56 + (t % 3);    // tap offset in slab px units
    __builtin_amdgcn_s_setprio(1);
#pragma unroll
    for (int kk = 0; kk < 4; ++kk) {
      i32x4 bf0, bf1;
      {
        int ps0 = psb[0] + dlt;
        int ps1 = psb[1] + dlt;
        bf0 = *(const i32x4*)(&lds[((ps0 << 7) + kk * 32 + h16) ^ ((ps0 & 7) << 4)]);
        bf1 = *(const i32x4*)(&lds[((ps1 << 7) + kk * 32 + h16) ^ ((ps1 & 7) << 4)]);
      }
#pragma unroll
      for (int m = 0; m < 2; ++m) {
        acc[m][0] = __builtin_amdgcn_mfma_i32_32x32x32_i8(af[t & 1][kk][m], bf0,
                                                          acc[m][0], 0, 0, 0);
        acc[m][1] = __builtin_amdgcn_mfma_i32_32x32x32_i8(af[t & 1][kk][m], bf1,
                                                          acc[m][1], 0, 0, 0);
      }
    }
    __builtin_amdgcn_s_setprio(0);
  }

  // ---- epilogue: C frag 32x32: px col = l&31, co row = (r&3) + 8*(r>>2) + 4*(l>>5)
  float* obase = out + ((size_t)(n * C_OUT + ct * 128)) * PXROW + y0 * W_OUT;
  const float* apx = asumf + (size_t)n * PXROW + y0 * W_OUT;
  float asf[2];
#pragma unroll
  for (int pf = 0; pf < 2; ++pf)
    asf[pf] = (jv[pf] < 108) ? apx[jv[pf]] : 0.0f;
  const int rbase = 4 * (l >> 5);
#pragma unroll
  for (int m = 0; m < 2; ++m) {
#pragma unroll
    for (int r = 0; r < 16; ++r) {
      int col = wr * 64 + m * 32 + (r & 3) + 8 * (r >> 2) + rbase;  // co in ctile
      float bc = bconst[ct * 128 + col];
      float* o = obase + (size_t)col * PXROW;
#pragma unroll
      for (int pf = 0; pf < 2; ++pf)
        if (jv[pf] < 108)
          o[jv[pf]] = 1e-4f * (float)acc[m][pf][r] + asf[pf] + bc;
    }
  }
}

// ---------------- fallback (tiny ws): naive direct conv
__global__ void conv_naive(const int* __restrict__ in, const int* __restrict__ w,
                           const float* __restrict__ bias, float* __restrict__ out) {
  size_t idx = (size_t)blockIdx.x * 256 + threadIdx.x;
  size_t total = (size_t)N_B * C_OUT * H_OUT * W_OUT;
  if (idx >= total) return;
  int x = idx % W_OUT; size_t t = idx / W_OUT;
  int y = t % H_OUT; t /= H_OUT;
  int co = t % C_OUT; int n = (int)(t / C_OUT);
  int acc = 0;
  for (int ci = 0; ci < C_IN; ++ci) {
    const int* ib = in + (((size_t)n * C_IN + ci) * H_IN + y) * W_IN + x;
    const int* wb = w + (((size_t)co * C_IN + ci) * 3) * 3;
    for (int kh = 0; kh < 3; ++kh)
      for (int kw = 0; kw < 3; ++kw)
        acc += (ib[kh * W_IN + kw] - 7) * (wb[kh * 3 + kw] - 3);
  }
  float r = rintf(bias[co] / 0.0001f);
  r = fminf(fmaxf(r, -2147483648.0f), 2147483647.0f);
  out[idx] = (float)acc * (0.01f * 0.01f) + r * 0.0001f;
}

extern "C" void kernel_launch(void* const* d_in, const int* in_sizes, int n_in,
                              void* d_out, int out_size, void* d_ws, size_t ws_size,
                              hipStream_t stream) {
  const int*   in   = (const int*)d_in[0];
  const int*   w    = (const int*)d_in[1];
  const float* bias = (const float*)d_in[2];
  float*       out  = (float*)d_out;

  const size_t WQ_OFF = 0;                        // 294912
  const size_t IP_OFF = 294912;                   // 12845056
  const size_t RS_OFF = IP_OFF + 12845056;        // 401408
  const size_t AF_OFF = RS_OFF + 401408;          // 373248
  const size_t BC_OFF = AF_OFF + 373248;          // 1024
  const size_t NEED   = BC_OFF + 1024;

  if (ws_size >= NEED) {
    char* ws = (char*)d_ws;
    signed char* wq3  = (signed char*)(ws + WQ_OFF);
    signed char* ip   = (signed char*)(ws + IP_OFF);
    int*         rs   = (int*)(ws + RS_OFF);
    float*       af   = (float*)(ws + AF_OFF);
    float*       bc   = (float*)(ws + BC_OFF);

    repack_w<<<C_OUT, 128, 0, stream>>>(w, bias, wq3, bc);
    repack_in<<<dim3(H_IN, N_B), 256, 0, stream>>>(in, ip, rs);
    asum_k<<<(NPX + 255) / 256, 256, 0, stream>>>(rs, af);
    conv_mfma<<<dim3(27, N_B, 2), 256, 0, stream>>>(ip, wq3, af, bc, out);
  } else {
    size_t total = (size_t)N_B * C_OUT * H_OUT * W_OUT;
    conv_naive<<<(total + 255) / 256, 256, 0, stream>>>(in, w, bias, out);
  }
}